// Round 6
// baseline (601.116 us; speedup 1.0000x reference)
//
#include <hip/hip_runtime.h>
#include <math.h>

// DRC via exact max-affine scan parallelization, 255-step blocks.
// z' = max_{j=0..255}( aA^j aR^(255-j) z + M_j ); M_j via exact DP in passA.
// chain v3: 16 intercepts per lane within a 16-lane row; all 4 rows of the
// wave compute the identical chain redundantly -> reduction needs only 4
// in-row DPP hops, no readlane/SGPR feedback. Depth-3 static prefetch.
// passA / pass3 identical to previous round (controlled experiment).

#define SRATE 44100.0f
#define KSTEP 255
#define INTC  256
#define TILE2 32
#define NEG_INF -1e38f

static __device__ __forceinline__ float san(float p){
    p = isnan(p) ? 0.0f : p;
    p = (p == 0.0f) ? 1e-10f : p;
    return p;
}

struct Consts {
    float thr, invr, knee, i2k;
    float aA, aR, kAs, kRs, s;
    float mk;
    float LA, LR;    // log2(aA), log2(aR), exact analytic form
};

static __device__ __forceinline__ Consts get_consts(const float* __restrict__ P, int b){
    float p0 = san(P[b*6+0]);
    float p1 = san(P[b*6+1]);
    float p2 = san(P[b*6+2]);
    float p3 = san(P[b*6+3]);
    float p4 = san(P[b*6+4]);
    float p5 = san(P[b*6+5]);
    Consts c;
    c.thr  = -p0 * 60.0f;
    float ratio = p1 * 10.0f;
    c.invr = 1.0f / ratio;
    float atk = fmaxf(p2 / 10.0f, 1e-4f);
    float rel = fmaxf(p3 * 3.0f, 0.005f);
    c.knee = p4 * 24.0f;
    c.i2k  = 1.0f / (2.0f * c.knee);
    const float LOG9 = 2.1972245773362196f;
    const float INVLN2 = 1.4426950408889634f;
    c.aA = expf(-LOG9 / (SRATE * atk));
    c.aR = expf(-LOG9 / (SRATE * rel));
    c.LA = (-LOG9 / (SRATE * atk)) * INVLN2;
    c.LR = (-LOG9 / (SRATE * rel)) * INVLN2;
    c.s  = (c.aA <= c.aR) ? 1.0f : -1.0f;
    c.kAs = c.s * (1.0f - c.aA);
    c.kRs = c.s * (1.0f - c.aR);
    c.mk = exp2f((p5 * 20.0f) * 0.16609640474436813f);
    return c;
}

static __device__ __forceinline__ float compute_xl(float xin, const Consts& c){
    float ax = fabsf(xin) + 1e-8f;
    float xg = fmaxf(20.0f * log10f(ax), -96.0f);
    float d  = xg - c.thr;
    float t2 = d + d;
    float u  = (d + c.knee) * 0.5f;
    float yk = xg + (c.invr * (u * u)) * c.i2k;
    float ya = c.thr + d * c.invr;
    float yg = (t2 < -c.knee) ? xg : ((t2 > c.knee) ? ya : yk);
    return xg - yg;
}

template<int CTRL>
static __device__ __forceinline__ float maxdpp(float v){
    int t = __builtin_amdgcn_update_dpp(__float_as_int(v), __float_as_int(v),
                                        CTRL, 0xF, 0xF, false);
    return fmaxf(v, __int_as_float(t));
}

static __device__ __forceinline__ float rdlane(float v, int l){
    return __int_as_float(__builtin_amdgcn_readlane(__float_as_int(v), l));
}

// one DP step over new sample xli (updates M0..M3 in reverse so old values
// are consumed; p3 = old M3 from lane-1 = old M_{4l-1})
#define STEPA(xli) { \
    float ca = c.kAs * (xli); \
    float cr = c.kRs * (xli); \
    float p3 = __shfl_up(M3, 1, 64); \
    p3 = (lane == 0) ? NEG_INF : p3; \
    M3 = fmaxf(fmaf(c.aA, M2, ca), fmaf(c.aR, M3, cr)); \
    M2 = fmaxf(fmaf(c.aA, M1, ca), fmaf(c.aR, M2, cr)); \
    M1 = fmaxf(fmaf(c.aA, M0, ca), fmaf(c.aR, M1, cr)); \
    M0 = fmaxf(fmaf(c.aA, p3, ca), fmaf(c.aR, M0, cr)); \
}

// ---------------- passA: per-block 255-step DP (unchanged) ----------------
__global__ __launch_bounds__(256) void drc_passA(
    const float* __restrict__ x, const float* __restrict__ P,
    float* __restrict__ Mout, float* __restrict__ Movf,
    int N, int NBLK, int tailSteps, unsigned CAP4)
{
    const int lane = threadIdx.x & 63;
    const int gw = blockIdx.x * 4 + (threadIdx.x >> 6);
    const int batch = blockIdx.y;
    if (gw >= NBLK) return;
    Consts c = get_consts(P, batch);
    const int t = (gw == NBLK - 1) ? tailSteps : KSTEP;
    const size_t base = (size_t)batch * N;
    const int n0 = 2 + KSTEP * gw;

    const int i0 = n0 + 4 * lane;
    float xl0 = compute_xl(x[base + min(i0 + 0, N - 1)], c);
    float xl1 = compute_xl(x[base + min(i0 + 1, N - 1)], c);
    float xl2 = compute_xl(x[base + min(i0 + 2, N - 1)], c);
    float xl3 = compute_xl(x[base + min(i0 + 3, N - 1)], c);

    float M0 = (lane == 0) ? 0.0f : NEG_INF;
    float M1 = NEG_INF, M2 = NEG_INF, M3 = NEG_INF;

    if (t == KSTEP){
        for (int g = 0; g < 64; ++g){
            float xa0 = rdlane(xl0, g);
            float xa1 = rdlane(xl1, g);
            float xa2 = rdlane(xl2, g);
            float xa3 = rdlane(xl3, g);
            STEPA(xa0);
            STEPA(xa1);
            STEPA(xa2);
            if (g < 63) { STEPA(xa3); }   // 255 = 63*4 + 3
        }
    } else {
        for (int g = 0; g < 64; ++g){
            int ib = 4 * g;
            if (ib >= t) break;
            float xa0 = rdlane(xl0, g);
            float xa1 = rdlane(xl1, g);
            float xa2 = rdlane(xl2, g);
            float xa3 = rdlane(xl3, g);
            if (ib + 0 < t) { STEPA(xa0); }
            if (ib + 1 < t) { STEPA(xa1); }
            if (ib + 2 < t) { STEPA(xa2); }
            if (ib + 3 < t) { STEPA(xa3); }
        }
    }

    const size_t f4 = ((size_t)batch * NBLK + gw) * 64 + lane;
    float4 v = { M0, M1, M2, M3 };
    if (f4 < CAP4) ((float4*)Mout)[f4] = v;
    else           ((float4*)Movf)[f4 - CAP4] = v;
}

// ---------------- chain v3: 1 block per batch ----------------
// 16-lane rows; lane rl=lane&15 holds intercepts 16rl..16rl+15 (float4s
// q=4rl..4rl+3 of the block's 64-float4 record). LDS swizzle q'=q^((q>>2)&7)
// kills the 64B-stride bank conflict. 4 DPP hops give the row max in all
// lanes; rows are redundant so every lane holds z with zero extra hops.
#define SLP(e) exp2f((float)(16*rl+(e)) * c.LA + (float)(KSTEP-16*rl-(e)) * c.LR)

#define BODY(M0v,M1v,M2v,M3v,bb) { \
    const int b_ = (bb); \
    if (lane == (b_ & 63)) eacc = z; \
    float l0=fmaf(s0,z,M0v.x), l1=fmaf(s1,z,M0v.y), l2=fmaf(s2,z,M0v.z), l3=fmaf(s3,z,M0v.w); \
    float l4=fmaf(s4,z,M1v.x), l5=fmaf(s5,z,M1v.y), l6=fmaf(s6,z,M1v.z), l7=fmaf(s7,z,M1v.w); \
    float l8=fmaf(s8,z,M2v.x), l9=fmaf(s9,z,M2v.y), l10=fmaf(s10,z,M2v.z), l11=fmaf(s11,z,M2v.w); \
    float l12=fmaf(s12,z,M3v.x), l13=fmaf(s13,z,M3v.y), l14=fmaf(s14,z,M3v.z), l15=fmaf(s15,z,M3v.w); \
    float u0=fmaxf(fmaxf(l0,l1),fmaxf(l2,l3)); \
    float u1=fmaxf(fmaxf(l4,l5),fmaxf(l6,l7)); \
    float u2=fmaxf(fmaxf(l8,l9),fmaxf(l10,l11)); \
    float u3=fmaxf(fmaxf(l12,l13),fmaxf(l14,l15)); \
    float v_=fmaxf(fmaxf(u0,u1),fmaxf(u2,u3)); \
    v_=maxdpp<0xB1>(v_); v_=maxdpp<0x4E>(v_); \
    v_=maxdpp<0x141>(v_); v_=maxdpp<0x140>(v_); \
    z=v_; \
    if ((b_ & 63) == 63){ ent[ebase+lane]=eacc; ebase+=64; } \
}

#define LD(d0,d1,d2,d3, idx) { \
    const float4* sb4_ = (const float4*)sb; \
    int ii_ = (idx) * 64; \
    d0 = sb4_[ii_ + q0s]; d1 = sb4_[ii_ + q1s]; \
    d2 = sb4_[ii_ + q2s]; d3 = sb4_[ii_ + q3s]; \
}

__global__ __launch_bounds__(192) void drc_chain(
    const float* __restrict__ x, const float* __restrict__ P,
    const float* __restrict__ Mout, const float* __restrict__ Movf,
    float* __restrict__ entries, int N, int NBLK, unsigned CAP4)
{
    const int batch = blockIdx.x;
    const int tid = threadIdx.x;
    const int lane = tid & 63;
    const int rl = lane & 15;
    const int w = tid >> 6;
    Consts c = get_consts(P, batch);

    __shared__ float sM[2][TILE2 * INTC];   // 64 KiB

    const float4* outM4 = (const float4*)Mout;
    const float4* ovf4  = (const float4*)Movf;
    float* ent = entries + (size_t)batch * NBLK;

    // swizzled read offsets for this lane's 4 float4s
    const int q0s = (4*rl + 0) ^ (rl & 7);
    const int q1s = (4*rl + 1) ^ (rl & 7);
    const int q2s = (4*rl + 2) ^ (rl & 7);
    const int q3s = (4*rl + 3) ^ (rl & 7);

    // 16 slopes: j = 16*rl + e
    float s0=SLP(0), s1=SLP(1), s2=SLP(2), s3=SLP(3);
    float s4=SLP(4), s5=SLP(5), s6=SLP(6), s7=SLP(7);
    float s8=SLP(8), s9=SLP(9), s10=SLP(10), s11=SLP(11);
    float s12=SLP(12), s13=SLP(13), s14=SLP(14), s15=SLP(15);

    // prologue: sample 1 from y0 = 0
    float xl1v = compute_xl(x[(size_t)batch * N + 1], c);
    float z = fmaxf(c.kAs * xl1v, c.kRs * xl1v);

    const int NMAIN = NBLK - 1;              // tail block peeled (pass3 replays it)
    const int ntiles = (NMAIN + TILE2 - 1) / TILE2;

    auto loadM4 = [&](size_t f4) -> float4 {
        return (f4 < CAP4) ? outM4[f4] : ovf4[f4 - CAP4];
    };

    auto stage = [&](int tile, int buf){
        const int sI = tid - 64;             // 0..127
        const int b0 = tile * TILE2;
        const int cnt = min(TILE2, NMAIN - b0);
        const int total4 = cnt * 64;
        const size_t fb = ((size_t)batch * NBLK + b0) * 64;
        float4* dst = (float4*)&sM[buf][0];
        if (total4 == TILE2 * 64){
            float4 tmp[16];
            #pragma unroll
            for (int k = 0; k < 16; ++k) tmp[k] = loadM4(fb + (size_t)k * 128 + sI);
            #pragma unroll
            for (int k = 0; k < 16; ++k){
                int q  = k * 128 + sI;
                int lq = q & 63;
                int qs = (q & ~63) | (lq ^ ((lq >> 2) & 7));
                dst[qs] = tmp[k];
            }
        } else {
            for (int q = sI; q < total4; q += 128){
                int lq = q & 63;
                int qs = (q & ~63) | (lq ^ ((lq >> 2) & 7));
                dst[qs] = loadM4(fb + q);
            }
        }
    };

    if (w > 0 && ntiles > 0) stage(0, 0);
    __syncthreads();

    float eacc = 0.0f;
    int ebase = 0;

    for (int tile = 0; tile < ntiles; ++tile){
        const int buf = tile & 1;
        if (w > 0){
            if (tile + 1 < ntiles) stage(tile + 1, buf ^ 1);
        } else {
            const int b0 = tile * TILE2;
            const int cnt = min(TILE2, NMAIN - b0);
            const float* sb = &sM[buf][0];
            float4 A0,A1,A2,A3, B0,B1,B2,B3, C0,C1,C2,C3;
            LD(A0,A1,A2,A3, 0)
            LD(B0,B1,B2,B3, min(1, cnt - 1))
            LD(C0,C1,C2,C3, min(2, cnt - 1))
            int it = 0;
            for (; it + 3 <= cnt; it += 3){
                BODY(A0,A1,A2,A3, b0 + it)
                LD(A0,A1,A2,A3, min(it + 3, cnt - 1))
                BODY(B0,B1,B2,B3, b0 + it + 1)
                LD(B0,B1,B2,B3, min(it + 4, cnt - 1))
                BODY(C0,C1,C2,C3, b0 + it + 2)
                LD(C0,C1,C2,C3, min(it + 5, cnt - 1))
            }
            if (it     < cnt){ BODY(A0,A1,A2,A3, b0 + it)     }
            if (it + 1 < cnt){ BODY(B0,B1,B2,B3, b0 + it + 1) }
            if (it + 2 < cnt){ BODY(C0,C1,C2,C3, b0 + it + 2) }
        }
        __syncthreads();
    }

    if (w == 0){
        const int bT = NBLK - 1;
        if (lane == (bT & 63)) eacc = z;         // entry for peeled tail block
        const int rem = NBLK - ebase;
        if (lane < rem) ent[ebase + lane] = eacc;
    }
}

// ---------------- pass3: replay each block from exact entry (unchanged) ----------------
__global__ __launch_bounds__(256) void drc_pass3(
    const float* __restrict__ x, const float* __restrict__ P,
    const float* __restrict__ entries, float* __restrict__ out,
    int N, int NBLK, int tailSteps, int B)
{
    const int gid = blockIdx.x * blockDim.x + threadIdx.x;
    const int batch = gid / NBLK;
    if (batch >= B) return;
    const int b = gid - batch * NBLK;
    Consts c = get_consts(P, batch);
    const float KL = 0.16609640474436813f;   // log2(10)/20
    const size_t base = (size_t)batch * N;

    float z = entries[(size_t)batch * NBLK + b];
    if (b == 0){
        float x0 = x[base + 0];
        float y0 = x0 * c.mk;                 // y_L[0] = 0 -> gain 1
        out[base + 0] = isfinite(y0) ? y0 : 0.0f;
        float x1 = x[base + 1];
        float yl1 = fmaxf(c.s * z, -96.0f);   // entry[0] == y_1 (z-space)
        float y1 = x1 * (exp2f(-yl1 * KL) * c.mk);
        out[base + 1] = isfinite(y1) ? y1 : 0.0f;
    }
    const int t = (b == NBLK - 1) ? tailSteps : KSTEP;
    const int n0 = 2 + b * KSTEP;

    #define P3STEP(xv) { \
        float xl = compute_xl(xv, c); \
        z = fmaxf(fmaf(c.aA, z, c.kAs * xl), fmaf(c.aR, z, c.kRs * xl)); }
    #define P3OUT(xv, dst) { \
        float yl = fmaxf(c.s * z, -96.0f); \
        float y = (xv) * (exp2f(-yl * KL) * c.mk); \
        dst = isfinite(y) ? y : 0.0f; }

    int i = 0;
    for (; i + 4 <= t; i += 4){
        const size_t n = base + n0 + i;
        float a0 = x[n + 0];
        float a1 = x[n + 1];
        float a2 = x[n + 2];
        float a3 = x[n + 3];
        float o0, o1, o2, o3;
        P3STEP(a0); P3OUT(a0, o0);
        P3STEP(a1); P3OUT(a1, o1);
        P3STEP(a2); P3OUT(a2, o2);
        P3STEP(a3); P3OUT(a3, o3);
        out[n + 0] = o0; out[n + 1] = o1; out[n + 2] = o2; out[n + 3] = o3;
    }
    for (; i < t; ++i){
        const size_t n = base + n0 + i;
        float a = x[n];
        float o;
        P3STEP(a); P3OUT(a, o);
        out[n] = o;
    }
}

extern "C" void kernel_launch(void* const* d_in, const int* in_sizes, int n_in,
                              void* d_out, int out_size, void* d_ws, size_t ws_size,
                              hipStream_t stream){
    const float* x = (const float*)d_in[0];
    const float* P = (const float*)d_in[1];
    float* out = (float*)d_out;
    float* ws  = (float*)d_ws;

    const int B = in_sizes[1] / 6;
    const int N = in_sizes[0] / B;

    const int NBLK = (N - 2 + KSTEP - 1) / KSTEP;
    const int tailSteps = (N - 2) - (NBLK - 1) * KSTEP;

    const unsigned OUT_CAP = (unsigned)out_size;       // floats available in d_out
    const unsigned CAP4 = OUT_CAP / 4;

    float* entries = ws;
    size_t entN = (((size_t)B * NBLK) + 3) & ~(size_t)3;  // 16B-align overflow
    float* Movf = ws + entN;

    {
        dim3 g((NBLK + 3) / 4, B);
        drc_passA<<<g, 256, 0, stream>>>(x, P, out, Movf, N, NBLK, tailSteps, CAP4);
    }
    drc_chain<<<B, 192, 0, stream>>>(x, P, out, Movf, entries, N, NBLK, CAP4);
    {
        int total = B * NBLK;
        drc_pass3<<<(total + 255) / 256, 256, 0, stream>>>(x, P, entries, out,
                                                           N, NBLK, tailSteps, B);
    }
}